// Round 11
// baseline (8314.941 us; speedup 1.0000x reference)
//
#include <hip/hip_runtime.h>
#include <hip/hip_bf16.h>

typedef __attribute__((ext_vector_type(8))) short bf16x8;
typedef __attribute__((ext_vector_type(4))) float f32x4;

#define C2LE 2.8853900817779268f   // 2*log2(e)
#define LOG2E 1.4426950408889634f
#define AGENT __HIP_MEMORY_SCOPE_AGENT
#define RLX __ATOMIC_RELAXED

static __device__ __forceinline__ float blo(unsigned q) { return __uint_as_float(q << 16); }
static __device__ __forceinline__ float bhi(unsigned q) { return __uint_as_float(q & 0xFFFF0000u); }
static __device__ __forceinline__ float sigm(float x) {
  return __builtin_amdgcn_rcpf(1.0f + __builtin_amdgcn_exp2f(-x * LOG2E));
}
static __device__ __forceinline__ float tanhe(float x) {
  return fmaf(-2.0f, __builtin_amdgcn_rcpf(1.0f + __builtin_amdgcn_exp2f(x * C2LE)), 1.0f);
}
static __device__ __forceinline__ unsigned packhilo(float x) {
  __hip_bfloat16 h = __float2bfloat16(x);
  float r = x - __bfloat162float(h);
  __hip_bfloat16 l = __float2bfloat16(r);
  return (unsigned)__bfloat16_as_ushort(h) | ((unsigned)__bfloat16_as_ushort(l) << 16);
}
// paired uints (hi|lo<<16 per dim) -> hi/lo bf16x8 frags
static __device__ __forceinline__ void mkfrags(uint4 q0, uint4 q1, bf16x8& hi, bf16x8& lo) {
  uint4 h, l;
  h.x = __builtin_amdgcn_perm(q0.y, q0.x, 0x05040100u);
  h.y = __builtin_amdgcn_perm(q0.w, q0.z, 0x05040100u);
  h.z = __builtin_amdgcn_perm(q1.y, q1.x, 0x05040100u);
  h.w = __builtin_amdgcn_perm(q1.w, q1.z, 0x05040100u);
  l.x = __builtin_amdgcn_perm(q0.y, q0.x, 0x07060302u);
  l.y = __builtin_amdgcn_perm(q0.w, q0.z, 0x07060302u);
  l.z = __builtin_amdgcn_perm(q1.y, q1.x, 0x07060302u);
  l.w = __builtin_amdgcn_perm(q1.w, q1.z, 0x07060302u);
  hi = *(bf16x8*)&h;
  lo = *(bf16x8*)&l;
}
static __device__ __forceinline__ int swz(int e) { return e ^ ((e >> 4) & 7); }

// ---------------- pack kernels (validated layouts) ----------------
__global__ void k_pack_whB(const float* __restrict__ wue, __hip_bfloat16* __restrict__ wp) {
  for (int idx = blockIdx.x * blockDim.x + threadIdx.x; idx < 262144;
       idx += gridDim.x * blockDim.x) {
    int j = idx & 7, l = (idx >> 3) & 63, kap = (idx >> 9) & 15, nb = (idx >> 13) & 3,
        sl = idx >> 15;
    int o = sl * 64 + nb * 16 + (l & 15);
    int dim = kap * 32 + (l >> 4) * 8 + j;
    wp[idx] = __float2bfloat16(wue[o * 1024 + dim]);
  }
}
__global__ void k_pack_w3B(const float* __restrict__ wih, const float* __restrict__ whh,
                           __hip_bfloat16* __restrict__ wp) {
  for (int idx = blockIdx.x * blockDim.x + threadIdx.x; idx < 393216;
       idx += gridDim.x * blockDim.x) {
    int j = idx & 7, l = (idx >> 3) & 63;
    int ks = (idx >> 9) % 12, r = (idx >> 9) / 12;
    int nb = r & 7, sl = r >> 3;
    int n = nb * 16 + (l & 15);
    int g = (n >> 5) * 256 + sl * 32 + (n & 31);
    int k = ks * 32 + (l >> 4) * 8 + j;
    float v = (k < 128) ? wih[g * 128 + k] : whh[g * 256 + (k - 128)];
    wp[idx] = __float2bfloat16(v);
  }
}
__global__ void k_bsum(const float* __restrict__ bih, const float* __restrict__ bhh,
                       float* __restrict__ bs) {
  int idx = blockIdx.x * blockDim.x + threadIdx.x;
  if (idx < 1024) bs[idx] = bih[idx] + bhh[idx];
}
__global__ void k_wxt(const float* __restrict__ wue, float* __restrict__ wxt) {
  for (int idx = blockIdx.x * blockDim.x + threadIdx.x; idx < 512 * 512;
       idx += gridDim.x * blockDim.x) {
    int o = idx & 511, s = idx >> 9;
    wxt[idx] = wue[o * 1024 + 512 + s];
  }
}

// proj_x: px2[b][d][s] = bf16( exp2(C2LE * proj_x[b,d,s]) )   [Epx]
__global__ __launch_bounds__(512) void k_projx(const float* __restrict__ x,
                                               const float* __restrict__ wxt,
                                               __hip_bfloat16* __restrict__ px2) {
  __shared__ alignas(16) float xsT[32][512];
  const int b = blockIdx.x;
  const int tid = threadIdx.x;
  for (int dt = 0; dt < 4; ++dt) {
    __syncthreads();
    const float4* xr = (const float4*)(x + ((size_t)b << 16) + (size_t)tid * 128 + dt * 32);
#pragma unroll
    for (int q = 0; q < 8; ++q) {
      float4 vx = xr[q];
      xsT[q * 4 + 0][tid] = vx.x;
      xsT[q * 4 + 1][tid] = vx.y;
      xsT[q * 4 + 2][tid] = vx.z;
      xsT[q * 4 + 3][tid] = vx.w;
    }
    __syncthreads();
    const int o = tid;
    float acc[32];
#pragma unroll
    for (int dd = 0; dd < 32; ++dd) acc[dd] = 0.f;
    for (int s4 = 0; s4 < 128; ++s4) {
      float w0 = wxt[(s4 * 4 + 0) * 512 + o];
      float w1 = wxt[(s4 * 4 + 1) * 512 + o];
      float w2 = wxt[(s4 * 4 + 2) * 512 + o];
      float w3 = wxt[(s4 * 4 + 3) * 512 + o];
#pragma unroll
      for (int dd = 0; dd < 32; ++dd) {
        float4 xv = *(const float4*)&xsT[dd][s4 * 4];
        acc[dd] = fmaf(w0, xv.x, fmaf(w1, xv.y, fmaf(w2, xv.z, fmaf(w3, xv.w, acc[dd]))));
      }
    }
    for (int dd = 0; dd < 32; ++dd) {
      px2[((size_t)b * 128 + dt * 32 + dd) * 512 + o] =
          __float2bfloat16(__builtin_amdgcn_exp2f(acc[dd] * C2LE));
    }
  }
}

// ---------------- main persistent kernel: 32 groups x 8 blocks ----------------
// E exchange: tagged 8B slots (tag=t+1 | f32 partial), single buffer. Safe because
// barrier B guarantees all step-t E reads complete before any block writes E(t+1).
__global__ __launch_bounds__(1024) void k_main(
    const __hip_bfloat16* __restrict__ px2, const __hip_bfloat16* __restrict__ whB,
    const __hip_bfloat16* __restrict__ w3B, const float* __restrict__ bsum,
    const float* __restrict__ x, const float* __restrict__ ve,
    unsigned* __restrict__ hG, unsigned long long* __restrict__ Eg,
    unsigned* __restrict__ ctrs, float* __restrict__ out) {
  __shared__ alignas(16) __hip_bfloat16 w3_l[49152];  // 96 KB W3 B-frags
  __shared__ alignas(16) uint4 hA0[1024];             // 16 KB (q0 halves, swizzled)
  __shared__ alignas(16) uint4 hA1[1024];             // 16 KB (q1 halves)
  __shared__ alignas(16) uint4 uA0[256];              // 4 KB
  __shared__ alignas(16) uint4 uA1[256];              // 4 KB
  __shared__ float PHp[4][8][64];                     // 8 KB
  __shared__ float PH[512];                           // 2 KB   ePH = exp2(C2LE*ph)
  __shared__ float gp[2][128][9];                     // 9 KB (padded stride)
  __shared__ float c_l[32][8];                        // 1 KB
  __shared__ float v_l[64];
  __shared__ float bs_l[128];
  __shared__ float zpart[16];
  __shared__ float vss_sh;

  const int grp = blockIdx.x & 31;  // 8 member blocks share blockIdx%32 -> same XCD
  const int sl = blockIdx.x >> 5;   // slice 0..7
  const int tid = threadIdx.x;
  const int lane = tid & 63;
  const int w = tid >> 6;
  const int b = tid >> 7;  // phase2/softmax mapping
  const int d = tid & 127;
  const int bG = grp * 8 + b;

  // ---- prologue
  {
    const uint4* src = (const uint4*)(w3B + (size_t)sl * 49152);
    uint4* dst = (uint4*)w3_l;
    for (int i = tid; i < 6144; i += 1024) dst[i] = src[i];
  }
  bf16x8 whr[4];
  {
    const bf16x8* src =
        (const bf16x8*)whB + ((size_t)(sl * 4 + (w & 3)) * 16 + (w >> 2) * 4) * 64 + lane;
#pragma unroll
    for (int i = 0; i < 4; ++i) whr[i] = src[i * 64];
  }
  uint4 pxr[8];  // bf16 Epx pairs for our (b,d), 64 s
  {
    const uint4* p4 = (const uint4*)(px2 + ((size_t)bG * 128 + d) * 512 + sl * 64);
#pragma unroll
    for (int i = 0; i < 8; ++i) pxr[i] = p4[i];
  }
  if (tid < 64) v_l[tid] = ve[sl * 64 + tid];
  if (tid < 128) bs_l[tid] = bsum[(tid >> 5) * 256 + sl * 32 + (tid & 31)];
  if (tid < 256) c_l[tid >> 3][tid & 7] = 0.f;
  {
    uint4 z = {0, 0, 0, 0};
    hA0[tid] = z;
    hA1[tid] = z;
    if (tid < 256) {
      uA0[tid] = z;
      uA1[tid] = z;
    }
  }
  if (tid == 0) {
    float s = 0.f;
    for (int i = 0; i < 64; ++i) s += ve[sl * 64 + i];
    vss_sh = s;
  }
  __syncthreads();
  const float vss = vss_sh;
  unsigned* ctrB = ctrs + grp * 64 + 32;
  float xv = x[((size_t)bG * 512) * 128 + d];  // x for t=0

  for (int t = 0; t < 512; ++t) {
    const int par = t & 1;

    // ---- stage h/c (compact) from coherence point into swizzled split LDS arrays
    {
      const unsigned long long* hp =
          (const unsigned long long*)(hG + (size_t)(par * 32 + grp) * 4096) + tid * 2;
      unsigned long long a0 = __hip_atomic_load(hp, RLX, AGENT);
      unsigned long long a1 = __hip_atomic_load(hp + 1, RLX, AGENT);
      int p = tid * 4;
      int e = ((p >> 6) << 4) + ((p >> 3) & 7);
      int ep = swz(e);
      uint4 q;
      q.x = (unsigned)a0;
      q.y = (unsigned)(a0 >> 32);
      q.z = (unsigned)a1;
      q.w = (unsigned)(a1 >> 32);
      if (p & 4) hA1[ep] = q;
      else hA0[ep] = q;
    }
    __syncthreads();

    // ---- Phase 1: PH[8b, 64o] = hs x Wh (16 waves = 4nb x 4kq; hi+lo passes)
    {
      const int kq = w >> 2, nb = w & 3;
      f32x4 acc = {0.f, 0.f, 0.f, 0.f};
#pragma unroll
      for (int i = 0; i < 4; ++i) {
        int ep = swz((kq * 4 + i) * 64 + lane);
        uint4 q0 = hA0[ep], q1 = hA1[ep];
        bf16x8 ahi, alo;
        mkfrags(q0, q1, ahi, alo);
        acc = __builtin_amdgcn_mfma_f32_16x16x32_bf16(ahi, whr[i], acc, 0, 0, 0);
        acc = __builtin_amdgcn_mfma_f32_16x16x32_bf16(alo, whr[i], acc, 0, 0, 0);
      }
      if (lane < 32) {
        int r16 = lane >> 4, c16 = lane & 15;
#pragma unroll
        for (int rr = 0; rr < 4; ++rr) PHp[kq][r16 * 4 + rr][nb * 16 + c16] = acc[rr];
      }
    }
    __syncthreads();
    if (tid < 512) {
      float s = (PHp[0][tid >> 6][tid & 63] + PHp[1][tid >> 6][tid & 63] +
                 PHp[2][tid >> 6][tid & 63] + PHp[3][tid >> 6][tid & 63]);
      PH[tid] = __builtin_amdgcn_exp2f(s * C2LE);  // ePH
    }
    __syncthreads();

    // ---- Phase 2: E partial over our 64 s for (b,d): r = 1/(1 + Epx*ePH)
    {
      float R = 0.f;
      const float* PHb = &PH[b * 64];
#pragma unroll 2
      for (int s8 = 0; s8 < 8; ++s8) {
        uint4 q = pxr[s8];
        float4 pa = *(const float4*)&PHb[s8 * 8];
        float4 pb = *(const float4*)&PHb[s8 * 8 + 4];
        float4 va = *(const float4*)&v_l[s8 * 8];
        float4 vb = *(const float4*)&v_l[s8 * 8 + 4];
        R = fmaf(va.x, __builtin_amdgcn_rcpf(fmaf(blo(q.x), pa.x, 1.0f)), R);
        R = fmaf(va.y, __builtin_amdgcn_rcpf(fmaf(bhi(q.x), pa.y, 1.0f)), R);
        R = fmaf(va.z, __builtin_amdgcn_rcpf(fmaf(blo(q.y), pa.z, 1.0f)), R);
        R = fmaf(va.w, __builtin_amdgcn_rcpf(fmaf(bhi(q.y), pa.w, 1.0f)), R);
        R = fmaf(vb.x, __builtin_amdgcn_rcpf(fmaf(blo(q.z), pb.x, 1.0f)), R);
        R = fmaf(vb.y, __builtin_amdgcn_rcpf(fmaf(bhi(q.z), pb.y, 1.0f)), R);
        R = fmaf(vb.z, __builtin_amdgcn_rcpf(fmaf(blo(q.w), pb.z, 1.0f)), R);
        R = fmaf(vb.w, __builtin_amdgcn_rcpf(fmaf(bhi(q.w), pb.w, 1.0f)), R);
      }
      float part = fmaf(-2.f, R, vss);
      unsigned long long pk =
          ((unsigned long long)(unsigned)(t + 1) << 32) | (unsigned long long)__float_as_uint(part);
      __hip_atomic_store(Eg + ((size_t)grp * 8 + sl) * 1024 + b * 128 + d, pk, RLX, AGENT);
    }

    // ---- Phase 3h (h-part of gates; independent of softmax) hides E-store flight
    const int nb3 = w & 7, kh3 = w >> 3;
    f32x4 acc3 = {0.f, 0.f, 0.f, 0.f};
#pragma unroll
    for (int i = 0; i < 4; ++i) {
      int ks = 4 + kh3 * 4 + i;  // h ksteps 4..11 -> hA entries 0..7
      int ep = swz((ks - 4) * 64 + lane);
      uint4 q0 = hA0[ep], q1 = hA1[ep];
      bf16x8 ahi, alo;
      mkfrags(q0, q1, ahi, alo);
      bf16x8 bf = ((const bf16x8*)w3_l)[((size_t)nb3 * 12 + ks) * 64 + lane];
      acc3 = __builtin_amdgcn_mfma_f32_16x16x32_bf16(ahi, bf, acc3, 0, 0, 0);
      acc3 = __builtin_amdgcn_mfma_f32_16x16x32_bf16(alo, bf, acc3, 0, 0, 0);
    }

    // ---- tagged-poll E: wait for all 8 slices' partials for our (b,d); sum
    float Esum;
    {
      const unsigned long long* ep = Eg + (size_t)grp * 8192 + b * 128 + d;
      const unsigned tgt = (unsigned)(t + 1);
      unsigned long long v0, v1, v2, v3, v4, v5, v6, v7;
      for (;;) {
        v0 = __hip_atomic_load(ep + 0 * 1024, RLX, AGENT);
        v1 = __hip_atomic_load(ep + 1 * 1024, RLX, AGENT);
        v2 = __hip_atomic_load(ep + 2 * 1024, RLX, AGENT);
        v3 = __hip_atomic_load(ep + 3 * 1024, RLX, AGENT);
        v4 = __hip_atomic_load(ep + 4 * 1024, RLX, AGENT);
        v5 = __hip_atomic_load(ep + 5 * 1024, RLX, AGENT);
        v6 = __hip_atomic_load(ep + 6 * 1024, RLX, AGENT);
        v7 = __hip_atomic_load(ep + 7 * 1024, RLX, AGENT);
        bool ok = (unsigned)(v0 >> 32) >= tgt && (unsigned)(v1 >> 32) >= tgt &&
                  (unsigned)(v2 >> 32) >= tgt && (unsigned)(v3 >> 32) >= tgt &&
                  (unsigned)(v4 >> 32) >= tgt && (unsigned)(v5 >> 32) >= tgt &&
                  (unsigned)(v6 >> 32) >= tgt && (unsigned)(v7 >> 32) >= tgt;
        if (__all(ok)) break;
        __builtin_amdgcn_s_sleep(1);
      }
      Esum = ((__uint_as_float((unsigned)v0) + __uint_as_float((unsigned)v1)) +
              (__uint_as_float((unsigned)v2) + __uint_as_float((unsigned)v3))) +
             ((__uint_as_float((unsigned)v4) + __uint_as_float((unsigned)v5)) +
              (__uint_as_float((unsigned)v6) + __uint_as_float((unsigned)v7)));
    }

    // ---- softmax + u A-frag build
    float e = __builtin_amdgcn_exp2f(Esum * LOG2E);
    {
      float z = e;
#pragma unroll
      for (int m = 1; m < 64; m <<= 1) z += __shfl_xor(z, m);
      if (lane == 0) zpart[w] = z;
    }
    __syncthreads();
    {
      float zf = zpart[2 * b] + zpart[2 * b + 1];
      float u = xv * e * __builtin_amdgcn_rcpf(zf);
      int ep = swz((d >> 5) * 64 + ((d >> 3) & 3) * 16 + b);
      unsigned* dst = (d & 4) ? (unsigned*)&uA1[ep] : (unsigned*)&uA0[ep];
      dst[d & 3] = packhilo(u);
    }
    __syncthreads();

    // ---- Phase 3u: u-part of gates (ks 0..3)
#pragma unroll
    for (int i = 0; i < 2; ++i) {
      int ks = kh3 * 2 + i;
      int ep = swz(ks * 64 + lane);
      uint4 q0 = uA0[ep], q1 = uA1[ep];
      bf16x8 ahi, alo;
      mkfrags(q0, q1, ahi, alo);
      bf16x8 bf = ((const bf16x8*)w3_l)[((size_t)nb3 * 12 + ks) * 64 + lane];
      acc3 = __builtin_amdgcn_mfma_f32_16x16x32_bf16(ahi, bf, acc3, 0, 0, 0);
      acc3 = __builtin_amdgcn_mfma_f32_16x16x32_bf16(alo, bf, acc3, 0, 0, 0);
    }
    if (lane < 32) {
      int r16 = lane >> 4, c16 = lane & 15;
#pragma unroll
      for (int rr = 0; rr < 4; ++rr) gp[kh3][nb3 * 16 + c16][r16 * 4 + rr] = acc3[rr];
    }
    __syncthreads();

    // ---- Phase 4: LSTM pointwise (8b x 32jj); publish h/c
    float h_new;
    if (tid < 256) {
      int bb = tid & 7, jj = tid >> 3;
      float gi = gp[0][jj][bb] + gp[1][jj][bb] + bs_l[jj];
      float gf = gp[0][32 + jj][bb] + gp[1][32 + jj][bb] + bs_l[32 + jj];
      float gg = gp[0][64 + jj][bb] + gp[1][64 + jj][bb] + bs_l[64 + jj];
      float go = gp[0][96 + jj][bb] + gp[1][96 + jj][bb] + bs_l[96 + jj];
      float i_ = sigm(gi), f_ = sigm(gf), g_ = tanhe(gg), o_ = sigm(go);
      float c_new = fmaf(f_, c_l[jj][bb], i_ * g_);
      h_new = o_ * tanhe(c_new);
      c_l[jj][bb] = c_new;
      int dd = sl * 32 + jj;
      int p = (((dd >> 5) * 4 + ((dd >> 3) & 3)) * 8 + bb) * 8 + (dd & 7);
      unsigned* hw = hG + (size_t)((1 - par) * 32 + grp) * 4096;
      __hip_atomic_store(hw + p, packhilo(h_new), RLX, AGENT);
      __hip_atomic_store(hw + p + 2048, packhilo(c_new), RLX, AGENT);
    }
    // ---- barrier B (load-bearing: also guards single-par E-slot reuse);
    //      fill poll window with out-store + next-x prefetch
    __syncthreads();
    if (tid == 0) __hip_atomic_fetch_add(ctrB, 1u, RLX, AGENT);
    if (tid < 256) {
      int bb = tid & 7, jj = tid >> 3;
      __builtin_nontemporal_store(h_new,
                                  out + ((size_t)t * 256 + grp * 8 + bb) * 256 + sl * 32 + jj);
    }
    int tn = (t < 511) ? t + 1 : 511;
    float xv_n = x[((size_t)bG * 512 + tn) * 128 + d];
    if (tid == 0) {
      while (__hip_atomic_load(ctrB, RLX, AGENT) < 8u * (t + 1)) __builtin_amdgcn_s_sleep(1);
    }
    __syncthreads();
    xv = xv_n;
  }
}

// ---------------- host ----------------
extern "C" void kernel_launch(void* const* d_in, const int* in_sizes, int n_in,
                              void* d_out, int out_size, void* d_ws, size_t ws_size,
                              hipStream_t stream) {
  const float* x = (const float*)d_in[0];
  const float* wue = (const float*)d_in[1];
  const float* ve = (const float*)d_in[2];
  const float* wih = (const float*)d_in[3];
  const float* whh = (const float*)d_in[4];
  const float* bih = (const float*)d_in[5];
  const float* bhh = (const float*)d_in[6];
  float* out = (float*)d_out;

  char* ws = (char*)d_ws;
  __hip_bfloat16* px2 = (__hip_bfloat16*)(ws);             // 33,554,432 B
  __hip_bfloat16* whB = (__hip_bfloat16*)(ws + 33554432);  //    524,288 B
  __hip_bfloat16* w3B = (__hip_bfloat16*)(ws + 34078720);  //    786,432 B
  float* bsum = (float*)(ws + 34865152);                   //      4,096 B
  unsigned* ctrs = (unsigned*)(ws + 34869248);             //      8,192 B
  unsigned* hG = (unsigned*)(ws + 34877440);               //  1,048,576 B
  unsigned long long* Eg = (unsigned long long*)(ws + 35926016);  // 2,097,152 B (overlaid w/ wxt)
  float* wxt = (float*)(ws + 35926016);                    //  1,048,576 B (prep only)
  // total: 38,023,168 B

  k_pack_whB<<<1024, 256, 0, stream>>>(wue, whB);
  k_pack_w3B<<<1024, 256, 0, stream>>>(wih, whh, w3B);
  k_bsum<<<4, 256, 0, stream>>>(bih, bhh, bsum);
  k_wxt<<<256, 256, 0, stream>>>(wue, wxt);
  k_projx<<<256, 512, 0, stream>>>(x, wxt, px2);
  // after projx, wxt region is dead -> becomes Eg (must be zeroed: tag 0 < 1)
  hipMemsetAsync(hG, 0, 1048576, stream);
  hipMemsetAsync(Eg, 0, 2097152, stream);
  hipMemsetAsync(ctrs, 0, 8192, stream);
  k_main<<<256, 1024, 0, stream>>>(px2, whB, w3B, bsum, x, ve, hG, Eg, ctrs, out);
}

// Round 12
// 4575.699 us; speedup vs baseline: 1.8172x; 1.8172x over previous
//
#include <hip/hip_runtime.h>
#include <hip/hip_bf16.h>

typedef __attribute__((ext_vector_type(8))) short bf16x8;
typedef __attribute__((ext_vector_type(4))) float f32x4;

#define C2LE 2.8853900817779268f   // 2*log2(e)
#define LOG2E 1.4426950408889634f
#define AGENT __HIP_MEMORY_SCOPE_AGENT
#define RLX __ATOMIC_RELAXED

static __device__ __forceinline__ float blo(unsigned q) { return __uint_as_float(q << 16); }
static __device__ __forceinline__ float bhi(unsigned q) { return __uint_as_float(q & 0xFFFF0000u); }
static __device__ __forceinline__ float sigm(float x) {
  return __builtin_amdgcn_rcpf(1.0f + __builtin_amdgcn_exp2f(-x * LOG2E));
}
static __device__ __forceinline__ float tanhe(float x) {
  return fmaf(-2.0f, __builtin_amdgcn_rcpf(1.0f + __builtin_amdgcn_exp2f(x * C2LE)), 1.0f);
}
static __device__ __forceinline__ unsigned packhilo(float x) {
  __hip_bfloat16 h = __float2bfloat16(x);
  float r = x - __bfloat162float(h);
  __hip_bfloat16 l = __float2bfloat16(r);
  return (unsigned)__bfloat16_as_ushort(h) | ((unsigned)__bfloat16_as_ushort(l) << 16);
}
static __device__ __forceinline__ int swz(int e) { return e ^ ((e >> 4) & 7); }

// ---------------- pack kernels (validated layouts, unchanged) ----------------
__global__ void k_pack_whB(const float* __restrict__ wue, __hip_bfloat16* __restrict__ wp) {
  for (int idx = blockIdx.x * blockDim.x + threadIdx.x; idx < 262144;
       idx += gridDim.x * blockDim.x) {
    int j = idx & 7, l = (idx >> 3) & 63, kap = (idx >> 9) & 15, nb = (idx >> 13) & 3,
        sl = idx >> 15;
    int o = sl * 64 + nb * 16 + (l & 15);
    int dim = kap * 32 + (l >> 4) * 8 + j;
    wp[idx] = __float2bfloat16(wue[o * 1024 + dim]);
  }
}
__global__ void k_pack_w3B(const float* __restrict__ wih, const float* __restrict__ whh,
                           __hip_bfloat16* __restrict__ wp) {
  for (int idx = blockIdx.x * blockDim.x + threadIdx.x; idx < 393216;
       idx += gridDim.x * blockDim.x) {
    int j = idx & 7, l = (idx >> 3) & 63;
    int ks = (idx >> 9) % 12, r = (idx >> 9) / 12;
    int nb = r & 7, sl = r >> 3;
    int n = nb * 16 + (l & 15);
    int g = (n >> 5) * 256 + sl * 32 + (n & 31);
    int k = ks * 32 + (l >> 4) * 8 + j;
    float v = (k < 128) ? wih[g * 128 + k] : whh[g * 256 + (k - 128)];
    wp[idx] = __float2bfloat16(v);
  }
}
__global__ void k_bsum(const float* __restrict__ bih, const float* __restrict__ bhh,
                       float* __restrict__ bs) {
  int idx = blockIdx.x * blockDim.x + threadIdx.x;
  if (idx < 1024) bs[idx] = bih[idx] + bhh[idx];
}
__global__ void k_wxt(const float* __restrict__ wue, float* __restrict__ wxt) {
  for (int idx = blockIdx.x * blockDim.x + threadIdx.x; idx < 512 * 512;
       idx += gridDim.x * blockDim.x) {
    int o = idx & 511, s = idx >> 9;
    wxt[idx] = wue[o * 1024 + 512 + s];
  }
}

// proj_x: px2[b][d][s] = bf16( exp2(C2LE * proj_x[b,d,s]) )   [Epx]
__global__ __launch_bounds__(512) void k_projx(const float* __restrict__ x,
                                               const float* __restrict__ wxt,
                                               __hip_bfloat16* __restrict__ px2) {
  __shared__ alignas(16) float xsT[32][512];
  const int b = blockIdx.x;
  const int tid = threadIdx.x;
  for (int dt = 0; dt < 4; ++dt) {
    __syncthreads();
    const float4* xr = (const float4*)(x + ((size_t)b << 16) + (size_t)tid * 128 + dt * 32);
#pragma unroll
    for (int q = 0; q < 8; ++q) {
      float4 vx = xr[q];
      xsT[q * 4 + 0][tid] = vx.x;
      xsT[q * 4 + 1][tid] = vx.y;
      xsT[q * 4 + 2][tid] = vx.z;
      xsT[q * 4 + 3][tid] = vx.w;
    }
    __syncthreads();
    const int o = tid;
    float acc[32];
#pragma unroll
    for (int dd = 0; dd < 32; ++dd) acc[dd] = 0.f;
    for (int s4 = 0; s4 < 128; ++s4) {
      float w0 = wxt[(s4 * 4 + 0) * 512 + o];
      float w1 = wxt[(s4 * 4 + 1) * 512 + o];
      float w2 = wxt[(s4 * 4 + 2) * 512 + o];
      float w3 = wxt[(s4 * 4 + 3) * 512 + o];
#pragma unroll
      for (int dd = 0; dd < 32; ++dd) {
        float4 xv = *(const float4*)&xsT[dd][s4 * 4];
        acc[dd] = fmaf(w0, xv.x, fmaf(w1, xv.y, fmaf(w2, xv.z, fmaf(w3, xv.w, acc[dd]))));
      }
    }
    for (int dd = 0; dd < 32; ++dd) {
      px2[((size_t)b * 128 + dt * 32 + dd) * 512 + o] =
          __float2bfloat16(__builtin_amdgcn_exp2f(acc[dd] * C2LE));
    }
  }
}

// ---------------- main persistent kernel: 32 groups x 8 blocks (R10 structure) ----
// hG layout per (par,grp): 4096 uints = [hi: 512 entries x 4 words][lo: same].
// Entry E (h: 0..255 = P*8+bb, c: 256..511), word j2 = dim-pair. Frag-ready.
__global__ __launch_bounds__(1024) void k_main(
    const __hip_bfloat16* __restrict__ px2, const __hip_bfloat16* __restrict__ whB,
    const __hip_bfloat16* __restrict__ w3B, const float* __restrict__ bsum,
    const float* __restrict__ x, const float* __restrict__ ve,
    unsigned* __restrict__ hG, float* __restrict__ Eg, unsigned* __restrict__ ctrs,
    float* __restrict__ out) {
  __shared__ alignas(16) __hip_bfloat16 w3_l[49152];  // 96 KB W3 B-frags
  __shared__ alignas(16) uint4 hAhi[1024];            // 16 KB hi-frags (swizzled)
  __shared__ alignas(16) uint4 hAlo[1024];            // 16 KB lo-frags
  __shared__ alignas(16) uint4 uAhi[256];             // 4 KB
  __shared__ alignas(16) uint4 uAlo[256];             // 4 KB
  __shared__ float PHp[4][8][64];                     // 8 KB
  __shared__ float PH[512];                           // 2 KB   ePH = exp2(C2LE*ph)
  __shared__ float gp[2][128][9];                     // 9 KB (padded stride)
  __shared__ float c_l[32][9];                        // 1.1 KB (padded)
  __shared__ float v_l[64];
  __shared__ float bs_l[128];
  __shared__ float vss_sh;

  const int grp = blockIdx.x & 31;  // 8 member blocks share blockIdx%32 -> same XCD
  const int sl = blockIdx.x >> 5;   // slice 0..7
  const int tid = threadIdx.x;
  const int lane = tid & 63;
  const int w = tid >> 6;
  const int b2 = tid >> 7;  // phase2 mapping
  const int d2 = tid & 127;
  const int bG2 = grp * 8 + b2;

  // ---- prologue
  {
    const uint4* src = (const uint4*)(w3B + (size_t)sl * 49152);
    uint4* dst = (uint4*)w3_l;
    for (int i = tid; i < 6144; i += 1024) dst[i] = src[i];
  }
  bf16x8 whr[4];
  {
    const bf16x8* src =
        (const bf16x8*)whB + ((size_t)(sl * 4 + (w & 3)) * 16 + (w >> 2) * 4) * 64 + lane;
#pragma unroll
    for (int i = 0; i < 4; ++i) whr[i] = src[i * 64];
  }
  uint4 pxr[8];  // bf16 Epx pairs for our (b2,d2), 64 s
  {
    const uint4* p4 = (const uint4*)(px2 + ((size_t)bG2 * 128 + d2) * 512 + sl * 64);
#pragma unroll
    for (int i = 0; i < 8; ++i) pxr[i] = p4[i];
  }
  if (tid < 64) v_l[tid] = ve[sl * 64 + tid];
  if (tid < 128) bs_l[tid] = bsum[(tid >> 5) * 256 + sl * 32 + (tid & 31)];
  if (tid < 256) c_l[tid >> 3][tid & 7] = 0.f;
  {
    uint4 z = {0, 0, 0, 0};
    hAhi[tid] = z;
    hAlo[tid] = z;
    if (tid < 256) {
      uAhi[tid] = z;
      uAlo[tid] = z;
    }
  }
  if (tid == 0) {
    float s = 0.f;
    for (int i = 0; i < 64; ++i) s += ve[sl * 64 + i];
    vss_sh = s;
  }
  __syncthreads();
  const float vss = vss_sh;
  unsigned* ctrA = ctrs + grp * 64;
  unsigned* ctrB = ctrA + 32;
  // softmax-thread x data (tid<512): b = tid>>6, dims (2k, 2k+1), k = tid&63
  float2 xv2;
  if (tid < 512)
    xv2 = *(const float2*)&x[((size_t)(grp * 8 + (tid >> 6)) * 512) * 128 + 2 * (tid & 63)];

  for (int t = 0; t < 512; ++t) {
    const int par = t & 1;

    // ---- stage h/c hi/lo frag-words straight into LDS (no perms)
    {
      const unsigned long long* hp =
          (const unsigned long long*)(hG + (size_t)(par * 32 + grp) * 4096);
      int E = tid >> 1, which = tid & 1;
      const unsigned long long* src = hp + which * 1024 + E * 2;
      unsigned long long a0 = __hip_atomic_load(src, RLX, AGENT);
      unsigned long long a1 = __hip_atomic_load(src + 1, RLX, AGENT);
      int ep = swz(((E >> 3) << 4) + (E & 7));
      uint4 q;
      q.x = (unsigned)a0;
      q.y = (unsigned)(a0 >> 32);
      q.z = (unsigned)a1;
      q.w = (unsigned)(a1 >> 32);
      if (which) hAlo[ep] = q;
      else hAhi[ep] = q;
    }
    // zero next-par E slice (ours: 128 dwords)
    if (tid < 128)
      __hip_atomic_store(Eg + (size_t)((1 - par) * 32 + grp) * 1024 + sl * 128 + tid, 0.f, RLX,
                         AGENT);
    __syncthreads();

    // ---- Phase 1: PH[8b, 64o] = hs x Wh (16 waves = 4nb x 4kq; hi+lo passes)
    {
      const int kq = w >> 2, nb = w & 3;
      f32x4 acc = {0.f, 0.f, 0.f, 0.f};
#pragma unroll
      for (int i = 0; i < 4; ++i) {
        int ep = swz((kq * 4 + i) * 64 + lane);
        bf16x8 ahi = *(const bf16x8*)&hAhi[ep];
        bf16x8 alo = *(const bf16x8*)&hAlo[ep];
        acc = __builtin_amdgcn_mfma_f32_16x16x32_bf16(ahi, whr[i], acc, 0, 0, 0);
        acc = __builtin_amdgcn_mfma_f32_16x16x32_bf16(alo, whr[i], acc, 0, 0, 0);
      }
      if (lane < 32) {
        int r16 = lane >> 4, c16 = lane & 15;
#pragma unroll
        for (int rr = 0; rr < 4; ++rr) PHp[kq][r16 * 4 + rr][nb * 16 + c16] = acc[rr];
      }
    }
    __syncthreads();
    if (tid < 512) {
      float s = (PHp[0][tid >> 6][tid & 63] + PHp[1][tid >> 6][tid & 63] +
                 PHp[2][tid >> 6][tid & 63] + PHp[3][tid >> 6][tid & 63]);
      PH[tid] = __builtin_amdgcn_exp2f(s * C2LE);  // ePH
    }
    __syncthreads();

    // ---- Phase 2: E partial over our 64 s for (b2,d2): r = 1/(1 + Epx*ePH)
    {
      float R = 0.f;
      const float* PHb = &PH[b2 * 64];
#pragma unroll 2
      for (int s8 = 0; s8 < 8; ++s8) {
        uint4 q = pxr[s8];
        float4 pa = *(const float4*)&PHb[s8 * 8];
        float4 pb = *(const float4*)&PHb[s8 * 8 + 4];
        float4 va = *(const float4*)&v_l[s8 * 8];
        float4 vb = *(const float4*)&v_l[s8 * 8 + 4];
        R = fmaf(va.x, __builtin_amdgcn_rcpf(fmaf(blo(q.x), pa.x, 1.0f)), R);
        R = fmaf(va.y, __builtin_amdgcn_rcpf(fmaf(bhi(q.x), pa.y, 1.0f)), R);
        R = fmaf(va.z, __builtin_amdgcn_rcpf(fmaf(blo(q.y), pa.z, 1.0f)), R);
        R = fmaf(va.w, __builtin_amdgcn_rcpf(fmaf(bhi(q.y), pa.w, 1.0f)), R);
        R = fmaf(vb.x, __builtin_amdgcn_rcpf(fmaf(blo(q.z), pb.x, 1.0f)), R);
        R = fmaf(vb.y, __builtin_amdgcn_rcpf(fmaf(bhi(q.z), pb.y, 1.0f)), R);
        R = fmaf(vb.z, __builtin_amdgcn_rcpf(fmaf(blo(q.w), pb.z, 1.0f)), R);
        R = fmaf(vb.w, __builtin_amdgcn_rcpf(fmaf(bhi(q.w), pb.w, 1.0f)), R);
      }
      __hip_atomic_fetch_add(Eg + (size_t)(par * 32 + grp) * 1024 + b2 * 128 + d2,
                             fmaf(-2.f, R, vss), RLX, AGENT);
    }

    // ---- Phase 3h (h-part of gates) hides barrier A
    const int nb3 = w & 7, kh3 = w >> 3;
    f32x4 acc3 = {0.f, 0.f, 0.f, 0.f};
#pragma unroll
    for (int i = 0; i < 4; ++i) {
      int ks = 4 + kh3 * 4 + i;  // h ksteps 4..11 -> hA labels 0..511
      int ep = swz((ks - 4) * 64 + lane);
      bf16x8 ahi = *(const bf16x8*)&hAhi[ep];
      bf16x8 alo = *(const bf16x8*)&hAlo[ep];
      bf16x8 bf = ((const bf16x8*)w3_l)[((size_t)nb3 * 12 + ks) * 64 + lane];
      acc3 = __builtin_amdgcn_mfma_f32_16x16x32_bf16(ahi, bf, acc3, 0, 0, 0);
      acc3 = __builtin_amdgcn_mfma_f32_16x16x32_bf16(alo, bf, acc3, 0, 0, 0);
    }
    // ---- barrier A (leader RMW + leader poll; syncthreads drains E-adds first)
    __syncthreads();
    if (tid == 0) {
      __hip_atomic_fetch_add(ctrA, 1u, RLX, AGENT);
      while (__hip_atomic_load(ctrA, RLX, AGENT) < 8u * (t + 1)) __builtin_amdgcn_s_sleep(1);
    }
    __syncthreads();

    // ---- softmax (512 threads; one wave per batch; d-pairs; no zpart, no shfl for pairing)
    if (tid < 512) {
      const int bs = tid >> 6, k = tid & 63;
      float2 Ev = *(const float2*)&((
          const float*)Eg)[(size_t)(par * 32 + grp) * 1024 + bs * 128 + 2 * k];
      float e0 = __builtin_amdgcn_exp2f(Ev.x * LOG2E);
      float e1 = __builtin_amdgcn_exp2f(Ev.y * LOG2E);
      float z = e0 + e1;
#pragma unroll
      for (int m = 1; m < 64; m <<= 1) z += __shfl_xor(z, m);
      float zinv = __builtin_amdgcn_rcpf(z);
      float u0 = xv2.x * e0 * zinv, u1 = xv2.y * e1 * zinv;
      unsigned pk0 = packhilo(u0), pk1 = packhilo(u1);
      unsigned whi = __builtin_amdgcn_perm(pk1, pk0, 0x05040100u);
      unsigned wlo = __builtin_amdgcn_perm(pk1, pk0, 0x07060302u);
      int d0 = 2 * k;
      int ep = swz((d0 >> 5) * 64 + ((d0 >> 3) & 3) * 16 + bs);
      int j2 = (d0 >> 1) & 3;
      ((unsigned*)&uAhi[ep])[j2] = whi;
      ((unsigned*)&uAlo[ep])[j2] = wlo;
    }
    __syncthreads();

    // ---- Phase 3u: u-part of gates (ks 0..3)
#pragma unroll
    for (int i = 0; i < 2; ++i) {
      int ks = kh3 * 2 + i;
      int ep = swz(ks * 64 + lane);
      bf16x8 ahi = *(const bf16x8*)&uAhi[ep];
      bf16x8 alo = *(const bf16x8*)&uAlo[ep];
      bf16x8 bf = ((const bf16x8*)w3_l)[((size_t)nb3 * 12 + ks) * 64 + lane];
      acc3 = __builtin_amdgcn_mfma_f32_16x16x32_bf16(ahi, bf, acc3, 0, 0, 0);
      acc3 = __builtin_amdgcn_mfma_f32_16x16x32_bf16(alo, bf, acc3, 0, 0, 0);
    }
    if (lane < 32) {
      int r16 = lane >> 4, c16 = lane & 15;
#pragma unroll
      for (int rr = 0; rr < 4; ++rr) gp[kh3][nb3 * 16 + c16][r16 * 4 + rr] = acc3[rr];
    }
    __syncthreads();

    // ---- Phase 4: LSTM pointwise (coalesced mapping: bb=tid>>5, jj=tid&31)
    float h_new;
    int bb = tid >> 5, jj = tid & 31;
    if (tid < 256) {
      float gi = gp[0][jj][bb] + gp[1][jj][bb] + bs_l[jj];
      float gf = gp[0][32 + jj][bb] + gp[1][32 + jj][bb] + bs_l[32 + jj];
      float gg = gp[0][64 + jj][bb] + gp[1][64 + jj][bb] + bs_l[64 + jj];
      float go = gp[0][96 + jj][bb] + gp[1][96 + jj][bb] + bs_l[96 + jj];
      float i_ = sigm(gi), f_ = sigm(gf), g_ = tanhe(gg), o_ = sigm(go);
      float c_new = fmaf(f_, c_l[jj][bb], i_ * g_);
      h_new = o_ * tanhe(c_new);
      c_l[jj][bb] = c_new;
      // publish pre-split hi/lo words (pairs jj, jj^1 via shfl)
      unsigned pkh = packhilo(h_new), pkc = packhilo(c_new);
      unsigned prh = __shfl_xor(pkh, 1), prc = __shfl_xor(pkc, 1);
      int dd = sl * 32 + jj;
      int E = ((dd >> 5) * 4 + ((dd >> 3) & 3)) * 8 + bb;
      int j2 = (dd & 7) >> 1;
      unsigned* hw = hG + (size_t)((1 - par) * 32 + grp) * 4096;
      if ((jj & 1) == 0) {  // hi words: low16 = mine, high16 = partner
        __hip_atomic_store(hw + E * 4 + j2, __builtin_amdgcn_perm(prh, pkh, 0x05040100u), RLX,
                           AGENT);
        __hip_atomic_store(hw + (E + 256) * 4 + j2, __builtin_amdgcn_perm(prc, pkc, 0x05040100u),
                           RLX, AGENT);
      } else {  // lo words: low16 = partner's lo, high16 = mine's lo
        __hip_atomic_store(hw + 2048 + E * 4 + j2, __builtin_amdgcn_perm(pkh, prh, 0x07060302u),
                           RLX, AGENT);
        __hip_atomic_store(hw + 2048 + (E + 256) * 4 + j2,
                           __builtin_amdgcn_perm(pkc, prc, 0x07060302u), RLX, AGENT);
      }
    }
    // ---- barrier B; fill poll window with coalesced out-store + next-x prefetch
    __syncthreads();
    if (tid == 0) __hip_atomic_fetch_add(ctrB, 1u, RLX, AGENT);
    if (tid < 256)
      __builtin_nontemporal_store(h_new,
                                  out + ((size_t)t * 256 + grp * 8 + bb) * 256 + sl * 32 + jj);
    float2 xv2n;
    if (tid < 512) {
      int tn = (t < 511) ? t + 1 : 511;
      xv2n = *(const float2*)&x[((size_t)(grp * 8 + (tid >> 6)) * 512 + tn) * 128 + 2 * (tid & 63)];
    }
    if (tid == 0) {
      while (__hip_atomic_load(ctrB, RLX, AGENT) < 8u * (t + 1)) __builtin_amdgcn_s_sleep(1);
    }
    __syncthreads();
    xv2 = xv2n;
  }
}

// ---------------- host ----------------
extern "C" void kernel_launch(void* const* d_in, const int* in_sizes, int n_in,
                              void* d_out, int out_size, void* d_ws, size_t ws_size,
                              hipStream_t stream) {
  const float* x = (const float*)d_in[0];
  const float* wue = (const float*)d_in[1];
  const float* ve = (const float*)d_in[2];
  const float* wih = (const float*)d_in[3];
  const float* whh = (const float*)d_in[4];
  const float* bih = (const float*)d_in[5];
  const float* bhh = (const float*)d_in[6];
  float* out = (float*)d_out;

  char* ws = (char*)d_ws;
  __hip_bfloat16* px2 = (__hip_bfloat16*)(ws);             // 33,554,432 B
  __hip_bfloat16* whB = (__hip_bfloat16*)(ws + 33554432);  //    524,288 B
  __hip_bfloat16* w3B = (__hip_bfloat16*)(ws + 34078720);  //    786,432 B
  float* bsum = (float*)(ws + 34865152);                   //      4,096 B
  float* Eg = (float*)(ws + 34869248);                     //    262,144 B
  unsigned* ctrs = (unsigned*)(ws + 35131392);             //      8,192 B
  unsigned* hG = (unsigned*)(ws + 35139584);               //  1,048,576 B
  float* wxt = (float*)(ws + 36188160);                    //  1,048,576 B
  // total: 37,236,736 B

  k_pack_whB<<<1024, 256, 0, stream>>>(wue, whB);
  k_pack_w3B<<<1024, 256, 0, stream>>>(wih, whh, w3B);
  k_bsum<<<4, 256, 0, stream>>>(bih, bhh, bsum);
  k_wxt<<<256, 256, 0, stream>>>(wue, wxt);
  k_projx<<<256, 512, 0, stream>>>(x, wxt, px2);
  hipMemsetAsync(hG, 0, 1048576, stream);
  hipMemsetAsync(Eg, 0, 262144, stream);
  hipMemsetAsync(ctrs, 0, 8192, stream);
  k_main<<<256, 1024, 0, stream>>>(px2, whB, w3B, bsum, x, ve, hG, Eg, ctrs, out);
}

// Round 14
// 4527.467 us; speedup vs baseline: 1.8366x; 1.0107x over previous
//
#include <hip/hip_runtime.h>
#include <hip/hip_bf16.h>

typedef __attribute__((ext_vector_type(8))) short bf16x8;
typedef __attribute__((ext_vector_type(4))) float f32x4;

#define C2LE 2.8853900817779268f   // 2*log2(e)
#define LOG2E 1.4426950408889634f
#define AGENT __HIP_MEMORY_SCOPE_AGENT
#define RLX __ATOMIC_RELAXED

static __device__ __forceinline__ float blo(unsigned q) { return __uint_as_float(q << 16); }
static __device__ __forceinline__ float bhi(unsigned q) { return __uint_as_float(q & 0xFFFF0000u); }
static __device__ __forceinline__ float sigm(float x) {
  return __builtin_amdgcn_rcpf(1.0f + __builtin_amdgcn_exp2f(-x * LOG2E));
}
static __device__ __forceinline__ float tanhe(float x) {
  return fmaf(-2.0f, __builtin_amdgcn_rcpf(1.0f + __builtin_amdgcn_exp2f(x * C2LE)), 1.0f);
}
static __device__ __forceinline__ unsigned packhilo(float x) {
  __hip_bfloat16 h = __float2bfloat16(x);
  float r = x - __bfloat162float(h);
  __hip_bfloat16 l = __float2bfloat16(r);
  return (unsigned)__bfloat16_as_ushort(h) | ((unsigned)__bfloat16_as_ushort(l) << 16);
}
static __device__ __forceinline__ int swz(int e) { return e ^ ((e >> 4) & 7); }

// ---------------- pack kernels (validated layouts, unchanged) ----------------
__global__ void k_pack_whB(const float* __restrict__ wue, __hip_bfloat16* __restrict__ wp) {
  for (int idx = blockIdx.x * blockDim.x + threadIdx.x; idx < 262144;
       idx += gridDim.x * blockDim.x) {
    int j = idx & 7, l = (idx >> 3) & 63, kap = (idx >> 9) & 15, nb = (idx >> 13) & 3,
        sl = idx >> 15;
    int o = sl * 64 + nb * 16 + (l & 15);
    int dim = kap * 32 + (l >> 4) * 8 + j;
    wp[idx] = __float2bfloat16(wue[o * 1024 + dim]);
  }
}
__global__ void k_pack_w3B(const float* __restrict__ wih, const float* __restrict__ whh,
                           __hip_bfloat16* __restrict__ wp) {
  for (int idx = blockIdx.x * blockDim.x + threadIdx.x; idx < 393216;
       idx += gridDim.x * blockDim.x) {
    int j = idx & 7, l = (idx >> 3) & 63;
    int ks = (idx >> 9) % 12, r = (idx >> 9) / 12;
    int nb = r & 7, sl = r >> 3;
    int n = nb * 16 + (l & 15);
    int g = (n >> 5) * 256 + sl * 32 + (n & 31);
    int k = ks * 32 + (l >> 4) * 8 + j;
    float v = (k < 128) ? wih[g * 128 + k] : whh[g * 256 + (k - 128)];
    wp[idx] = __float2bfloat16(v);
  }
}
__global__ void k_bsum(const float* __restrict__ bih, const float* __restrict__ bhh,
                       float* __restrict__ bs) {
  int idx = blockIdx.x * blockDim.x + threadIdx.x;
  if (idx < 1024) bs[idx] = bih[idx] + bhh[idx];
}
__global__ void k_wxt(const float* __restrict__ wue, float* __restrict__ wxt) {
  for (int idx = blockIdx.x * blockDim.x + threadIdx.x; idx < 512 * 512;
       idx += gridDim.x * blockDim.x) {
    int o = idx & 511, s = idx >> 9;
    wxt[idx] = wue[o * 1024 + 512 + s];
  }
}

// proj_x: px2[b][d][s] = bf16( exp2(C2LE * proj_x[b,d,s]) )   [Epx]
__global__ __launch_bounds__(512) void k_projx(const float* __restrict__ x,
                                               const float* __restrict__ wxt,
                                               __hip_bfloat16* __restrict__ px2) {
  __shared__ alignas(16) float xsT[32][512];
  const int b = blockIdx.x;
  const int tid = threadIdx.x;
  for (int dt = 0; dt < 4; ++dt) {
    __syncthreads();
    const float4* xr = (const float4*)(x + ((size_t)b << 16) + (size_t)tid * 128 + dt * 32);
#pragma unroll
    for (int q = 0; q < 8; ++q) {
      float4 vx = xr[q];
      xsT[q * 4 + 0][tid] = vx.x;
      xsT[q * 4 + 1][tid] = vx.y;
      xsT[q * 4 + 2][tid] = vx.z;
      xsT[q * 4 + 3][tid] = vx.w;
    }
    __syncthreads();
    const int o = tid;
    float acc[32];
#pragma unroll
    for (int dd = 0; dd < 32; ++dd) acc[dd] = 0.f;
    for (int s4 = 0; s4 < 128; ++s4) {
      float w0 = wxt[(s4 * 4 + 0) * 512 + o];
      float w1 = wxt[(s4 * 4 + 1) * 512 + o];
      float w2 = wxt[(s4 * 4 + 2) * 512 + o];
      float w3 = wxt[(s4 * 4 + 3) * 512 + o];
#pragma unroll
      for (int dd = 0; dd < 32; ++dd) {
        float4 xv = *(const float4*)&xsT[dd][s4 * 4];
        acc[dd] = fmaf(w0, xv.x, fmaf(w1, xv.y, fmaf(w2, xv.z, fmaf(w3, xv.w, acc[dd]))));
      }
    }
    for (int dd = 0; dd < 32; ++dd) {
      px2[((size_t)b * 128 + dt * 32 + dd) * 512 + o] =
          __float2bfloat16(__builtin_amdgcn_exp2f(acc[dd] * C2LE));
    }
  }
}

// ---------------- main persistent kernel: 32 groups x 8 blocks (R12 structure) ----
__global__ __launch_bounds__(1024) void k_main(
    const __hip_bfloat16* __restrict__ px2, const __hip_bfloat16* __restrict__ whB,
    const __hip_bfloat16* __restrict__ w3B, const float* __restrict__ bsum,
    const float* __restrict__ x, const float* __restrict__ ve,
    unsigned* __restrict__ hG, float* __restrict__ Eg, unsigned* __restrict__ ctrs,
    float* __restrict__ out) {
  __shared__ alignas(16) __hip_bfloat16 w3_l[49152];  // 96 KB W3 B-frags
  __shared__ alignas(16) uint4 hAhi[1024];            // 16 KB hi-frags (swizzled)
  __shared__ alignas(16) uint4 hAlo[1024];            // 16 KB lo-frags
  __shared__ alignas(16) uint4 uAhi[256];             // 4 KB
  __shared__ alignas(16) uint4 uAlo[256];             // 4 KB
  __shared__ float PHp[4][8][64];                     // 8 KB
  __shared__ float PH[512];                           // 2 KB   ePH = exp2(C2LE*ph)
  __shared__ float gp[2][128][9];                     // 9 KB (padded stride)
  __shared__ float c_l[32][9];                        // 1.1 KB (padded)
  __shared__ float v_l[64];
  __shared__ float bs_l[128];
  __shared__ float vss_sh;

  const int grp = blockIdx.x & 31;  // 8 member blocks share blockIdx%32 -> same XCD
  const int sl = blockIdx.x >> 5;   // slice 0..7
  const int tid = threadIdx.x;
  const int lane = tid & 63;
  const int w = tid >> 6;
  const int b2 = tid >> 7;  // phase2 mapping
  const int d2 = tid & 127;
  const int bG2 = grp * 8 + b2;

  // ---- prologue
  {
    const uint4* src = (const uint4*)(w3B + (size_t)sl * 49152);
    uint4* dst = (uint4*)w3_l;
    for (int i = tid; i < 6144; i += 1024) dst[i] = src[i];
  }
  bf16x8 whr[4];
  {
    const bf16x8* src =
        (const bf16x8*)whB + ((size_t)(sl * 4 + (w & 3)) * 16 + (w >> 2) * 4) * 64 + lane;
#pragma unroll
    for (int i = 0; i < 4; ++i) whr[i] = src[i * 64];
  }
  uint4 pxr[8];  // bf16 Epx pairs for our (b2,d2), 64 s
  {
    const uint4* p4 = (const uint4*)(px2 + ((size_t)bG2 * 128 + d2) * 512 + sl * 64);
#pragma unroll
    for (int i = 0; i < 8; ++i) pxr[i] = p4[i];
  }
  if (tid < 64) v_l[tid] = ve[sl * 64 + tid];
  if (tid < 128) bs_l[tid] = bsum[(tid >> 5) * 256 + sl * 32 + (tid & 31)];
  if (tid < 256) c_l[tid >> 3][tid & 7] = 0.f;
  {
    uint4 z = {0, 0, 0, 0};
    hAhi[tid] = z;
    hAlo[tid] = z;
    if (tid < 256) {
      uAhi[tid] = z;
      uAlo[tid] = z;
    }
  }
  if (tid == 0) {
    float s = 0.f;
    for (int i = 0; i < 64; ++i) s += ve[sl * 64 + i];
    vss_sh = s;
  }
  __syncthreads();
  const float vss = vss_sh;
  unsigned* ctrA = ctrs + grp * 64;
  unsigned* ctrB = ctrA + 32;
  // softmax-thread x data (tid<512): b = tid>>6, dims (2k, 2k+1), k = tid&63
  float2 xv2;
  if (tid < 512)
    xv2 = *(const float2*)&x[((size_t)(grp * 8 + (tid >> 6)) * 512) * 128 + 2 * (tid & 63)];

  for (int t = 0; t < 512; ++t) {
    const int par = t & 1;

    // ---- stage h/c hi/lo frag-words straight into LDS (no perms)
    {
      const unsigned long long* hp =
          (const unsigned long long*)(hG + (size_t)(par * 32 + grp) * 4096);
      int E = tid >> 1, which = tid & 1;
      const unsigned long long* src = hp + which * 1024 + E * 2;
      unsigned long long a0 = __hip_atomic_load(src, RLX, AGENT);
      unsigned long long a1 = __hip_atomic_load(src + 1, RLX, AGENT);
      int ep = swz(((E >> 3) << 4) + (E & 7));
      uint4 q;
      q.x = (unsigned)a0;
      q.y = (unsigned)(a0 >> 32);
      q.z = (unsigned)a1;
      q.w = (unsigned)(a1 >> 32);
      if (which) hAlo[ep] = q;
      else hAhi[ep] = q;
    }
    // zero next-par E slice (ours: 128 dwords)
    if (tid < 128)
      __hip_atomic_store(Eg + (size_t)((1 - par) * 32 + grp) * 1024 + sl * 128 + tid, 0.f, RLX,
                         AGENT);
    __syncthreads();

    // ---- Phase 1: PH[8b, 64o] = hs x Wh (16 waves = 4nb x 4kq; hi+lo passes)
    {
      const int kq = w >> 2, nb = w & 3;
      f32x4 acc = {0.f, 0.f, 0.f, 0.f};
#pragma unroll
      for (int i = 0; i < 4; ++i) {
        int ep = swz((kq * 4 + i) * 64 + lane);
        bf16x8 ahi = *(const bf16x8*)&hAhi[ep];
        bf16x8 alo = *(const bf16x8*)&hAlo[ep];
        acc = __builtin_amdgcn_mfma_f32_16x16x32_bf16(ahi, whr[i], acc, 0, 0, 0);
        acc = __builtin_amdgcn_mfma_f32_16x16x32_bf16(alo, whr[i], acc, 0, 0, 0);
      }
      if (lane < 32) {
        int r16 = lane >> 4, c16 = lane & 15;
#pragma unroll
        for (int rr = 0; rr < 4; ++rr) PHp[kq][r16 * 4 + rr][nb * 16 + c16] = acc[rr];
      }
    }
    __syncthreads();
    if (tid < 512) {
      float s = (PHp[0][tid >> 6][tid & 63] + PHp[1][tid >> 6][tid & 63] +
                 PHp[2][tid >> 6][tid & 63] + PHp[3][tid >> 6][tid & 63]);
      PH[tid] = __builtin_amdgcn_exp2f(s * C2LE);  // ePH
    }
    __syncthreads();

    // ---- Phase 2: E partial over our 64 s for (b2,d2): r = 1/(1 + Epx*ePH)
    {
      float R = 0.f;
      const float* PHb = &PH[b2 * 64];
#pragma unroll 2
      for (int s8 = 0; s8 < 8; ++s8) {
        uint4 q = pxr[s8];
        float4 pa = *(const float4*)&PHb[s8 * 8];
        float4 pb = *(const float4*)&PHb[s8 * 8 + 4];
        float4 va = *(const float4*)&v_l[s8 * 8];
        float4 vb = *(const float4*)&v_l[s8 * 8 + 4];
        R = fmaf(va.x, __builtin_amdgcn_rcpf(fmaf(blo(q.x), pa.x, 1.0f)), R);
        R = fmaf(va.y, __builtin_amdgcn_rcpf(fmaf(bhi(q.x), pa.y, 1.0f)), R);
        R = fmaf(va.z, __builtin_amdgcn_rcpf(fmaf(blo(q.y), pa.z, 1.0f)), R);
        R = fmaf(va.w, __builtin_amdgcn_rcpf(fmaf(bhi(q.y), pa.w, 1.0f)), R);
        R = fmaf(vb.x, __builtin_amdgcn_rcpf(fmaf(blo(q.z), pb.x, 1.0f)), R);
        R = fmaf(vb.y, __builtin_amdgcn_rcpf(fmaf(bhi(q.z), pb.y, 1.0f)), R);
        R = fmaf(vb.z, __builtin_amdgcn_rcpf(fmaf(blo(q.w), pb.z, 1.0f)), R);
        R = fmaf(vb.w, __builtin_amdgcn_rcpf(fmaf(bhi(q.w), pb.w, 1.0f)), R);
      }
      __hip_atomic_fetch_add(Eg + (size_t)(par * 32 + grp) * 1024 + b2 * 128 + d2,
                             fmaf(-2.f, R, vss), RLX, AGENT);
    }

    // ---- Phase 3h part 1 (3 of 4 ksteps) hides the E-atomicAdd flight
    const int nb3 = w & 7, kh3 = w >> 3;
    f32x4 acc3 = {0.f, 0.f, 0.f, 0.f};
#pragma unroll
    for (int i = 0; i < 3; ++i) {
      int ks = 4 + kh3 * 4 + i;  // h ksteps 4..11 -> hA labels 0..511
      int ep = swz((ks - 4) * 64 + lane);
      bf16x8 ahi = *(const bf16x8*)&hAhi[ep];
      bf16x8 alo = *(const bf16x8*)&hAlo[ep];
      bf16x8 bf = ((const bf16x8*)w3_l)[((size_t)nb3 * 12 + ks) * 64 + lane];
      acc3 = __builtin_amdgcn_mfma_f32_16x16x32_bf16(ahi, bf, acc3, 0, 0, 0);
      acc3 = __builtin_amdgcn_mfma_f32_16x16x32_bf16(alo, bf, acc3, 0, 0, 0);
    }
    // ---- barrier A (leader RMW + leader poll; syncthreads drains E-adds first)
    __syncthreads();
    if (tid == 0) {
      __hip_atomic_fetch_add(ctrA, 1u, RLX, AGENT);
      while (__hip_atomic_load(ctrA, RLX, AGENT) < 8u * (t + 1)) __builtin_amdgcn_s_sleep(1);
    }
    __syncthreads();

    // ---- issue E read early (MALL RT), cover it with P3h part 2 (last kstep)
    float2 Ev;
    if (tid < 512)
      Ev = *(const float2*)&((
          const float*)Eg)[(size_t)(par * 32 + grp) * 1024 + (tid >> 6) * 128 + 2 * (tid & 63)];
    {
      int ks = 4 + kh3 * 4 + 3;
      int ep = swz((ks - 4) * 64 + lane);
      bf16x8 ahi = *(const bf16x8*)&hAhi[ep];
      bf16x8 alo = *(const bf16x8*)&hAlo[ep];
      bf16x8 bf = ((const bf16x8*)w3_l)[((size_t)nb3 * 12 + ks) * 64 + lane];
      acc3 = __builtin_amdgcn_mfma_f32_16x16x32_bf16(ahi, bf, acc3, 0, 0, 0);
      acc3 = __builtin_amdgcn_mfma_f32_16x16x32_bf16(alo, bf, acc3, 0, 0, 0);
    }

    // ---- softmax (512 threads; one wave per batch; d-pairs)
    if (tid < 512) {
      const int bs = tid >> 6, k = tid & 63;
      float e0 = __builtin_amdgcn_exp2f(Ev.x * LOG2E);
      float e1 = __builtin_amdgcn_exp2f(Ev.y * LOG2E);
      float z = e0 + e1;
#pragma unroll
      for (int m = 1; m < 64; m <<= 1) z += __shfl_xor(z, m);
      float zinv = __builtin_amdgcn_rcpf(z);
      float u0 = xv2.x * e0 * zinv, u1 = xv2.y * e1 * zinv;
      unsigned pk0 = packhilo(u0), pk1 = packhilo(u1);
      unsigned whi = __builtin_amdgcn_perm(pk1, pk0, 0x05040100u);
      unsigned wlo = __builtin_amdgcn_perm(pk1, pk0, 0x07060302u);
      int d0 = 2 * k;
      int ep = swz((d0 >> 5) * 64 + ((d0 >> 3) & 3) * 16 + bs);
      int j2 = (d0 >> 1) & 3;
      ((unsigned*)&uAhi[ep])[j2] = whi;
      ((unsigned*)&uAlo[ep])[j2] = wlo;
    }
    __syncthreads();

    // ---- Phase 3u: u-part of gates (ks 0..3)
#pragma unroll
    for (int i = 0; i < 2; ++i) {
      int ks = kh3 * 2 + i;
      int ep = swz(ks * 64 + lane);
      bf16x8 ahi = *(const bf16x8*)&uAhi[ep];
      bf16x8 alo = *(const bf16x8*)&uAlo[ep];
      bf16x8 bf = ((const bf16x8*)w3_l)[((size_t)nb3 * 12 + ks) * 64 + lane];
      acc3 = __builtin_amdgcn_mfma_f32_16x16x32_bf16(ahi, bf, acc3, 0, 0, 0);
      acc3 = __builtin_amdgcn_mfma_f32_16x16x32_bf16(alo, bf, acc3, 0, 0, 0);
    }
    if (lane < 32) {
      int r16 = lane >> 4, c16 = lane & 15;
#pragma unroll
      for (int rr = 0; rr < 4; ++rr) gp[kh3][nb3 * 16 + c16][r16 * 4 + rr] = acc3[rr];
    }
    __syncthreads();

    // ---- Phase 4: LSTM pointwise (coalesced mapping: bb=tid>>5, jj=tid&31)
    float h_new;
    int bb = tid >> 5, jj = tid & 31;
    if (tid < 256) {
      float gi = gp[0][jj][bb] + gp[1][jj][bb] + bs_l[jj];
      float gf = gp[0][32 + jj][bb] + gp[1][32 + jj][bb] + bs_l[32 + jj];
      float gg = gp[0][64 + jj][bb] + gp[1][64 + jj][bb] + bs_l[64 + jj];
      float go = gp[0][96 + jj][bb] + gp[1][96 + jj][bb] + bs_l[96 + jj];
      float i_ = sigm(gi), f_ = sigm(gf), g_ = tanhe(gg), o_ = sigm(go);
      float c_new = fmaf(f_, c_l[jj][bb], i_ * g_);
      h_new = o_ * tanhe(c_new);
      c_l[jj][bb] = c_new;
      // publish pre-split hi/lo words (pairs jj, jj^1 via shfl)
      unsigned pkh = packhilo(h_new), pkc = packhilo(c_new);
      unsigned prh = __shfl_xor(pkh, 1), prc = __shfl_xor(pkc, 1);
      int dd = sl * 32 + jj;
      int E = ((dd >> 5) * 4 + ((dd >> 3) & 3)) * 8 + bb;
      int j2 = (dd & 7) >> 1;
      unsigned* hw = hG + (size_t)((1 - par) * 32 + grp) * 4096;
      if ((jj & 1) == 0) {  // hi words: low16 = mine, high16 = partner
        __hip_atomic_store(hw + E * 4 + j2, __builtin_amdgcn_perm(prh, pkh, 0x05040100u), RLX,
                           AGENT);
        __hip_atomic_store(hw + (E + 256) * 4 + j2, __builtin_amdgcn_perm(prc, pkc, 0x05040100u),
                           RLX, AGENT);
      } else {  // lo words: low16 = partner's lo, high16 = mine's lo
        __hip_atomic_store(hw + 2048 + E * 4 + j2, __builtin_amdgcn_perm(pkh, prh, 0x07060302u),
                           RLX, AGENT);
        __hip_atomic_store(hw + 2048 + (E + 256) * 4 + j2,
                           __builtin_amdgcn_perm(pkc, prc, 0x07060302u), RLX, AGENT);
      }
    }
    // ---- barrier B; fill poll window with coalesced out-store + next-x prefetch
    __syncthreads();
    if (tid == 0) __hip_atomic_fetch_add(ctrB, 1u, RLX, AGENT);
    if (tid < 256)
      __builtin_nontemporal_store(h_new,
                                  out + ((size_t)t * 256 + grp * 8 + bb) * 256 + sl * 32 + jj);
    float2 xv2n;
    if (tid < 512) {
      int tn = (t < 511) ? t + 1 : 511;
      xv2n = *(const float2*)&x[((size_t)(grp * 8 + (tid >> 6)) * 512 + tn) * 128 + 2 * (tid & 63)];
    }
    if (tid == 0) {
      while (__hip_atomic_load(ctrB, RLX, AGENT) < 8u * (t + 1)) __builtin_amdgcn_s_sleep(1);
    }
    __syncthreads();
    xv2 = xv2n;
  }
}

// ---------------- host ----------------
extern "C" void kernel_launch(void* const* d_in, const int* in_sizes, int n_in,
                              void* d_out, int out_size, void* d_ws, size_t ws_size,
                              hipStream_t stream) {
  const float* x = (const float*)d_in[0];
  const float* wue = (const float*)d_in[1];
  const float* ve = (const float*)d_in[2];
  const float* wih = (const float*)d_in[3];
  const float* whh = (const float*)d_in[4];
  const float* bih = (const float*)d_in[5];
  const float* bhh = (const float*)d_in[6];
  float* out = (float*)d_out;

  char* ws = (char*)d_ws;
  __hip_bfloat16* px2 = (__hip_bfloat16*)(ws);             // 33,554,432 B
  __hip_bfloat16* whB = (__hip_bfloat16*)(ws + 33554432);  //    524,288 B
  __hip_bfloat16* w3B = (__hip_bfloat16*)(ws + 34078720);  //    786,432 B
  float* bsum = (float*)(ws + 34865152);                   //      4,096 B
  float* Eg = (float*)(ws + 34869248);                     //    262,144 B
  unsigned* ctrs = (unsigned*)(ws + 35131392);             //      8,192 B
  unsigned* hG = (unsigned*)(ws + 35139584);               //  1,048,576 B
  float* wxt = (float*)(ws + 36188160);                    //  1,048,576 B
  // total: 37,236,736 B

  k_pack_whB<<<1024, 256, 0, stream>>>(wue, whB);
  k_pack_w3B<<<1024, 256, 0, stream>>>(wih, whh, w3B);
  k_bsum<<<4, 256, 0, stream>>>(bih, bhh, bsum);
  k_wxt<<<256, 256, 0, stream>>>(wue, wxt);
  k_projx<<<256, 512, 0, stream>>>(x, wxt, px2);
  hipMemsetAsync(hG, 0, 1048576, stream);
  hipMemsetAsync(Eg, 0, 262144, stream);
  hipMemsetAsync(ctrs, 0, 8192, stream);
  k_main<<<256, 1024, 0, stream>>>(px2, whB, w3B, bsum, x, ve, hG, Eg, ctrs, out);
}

// Round 15
// 4526.345 us; speedup vs baseline: 1.8370x; 1.0002x over previous
//
#include <hip/hip_runtime.h>
#include <hip/hip_bf16.h>

typedef __attribute__((ext_vector_type(8))) short bf16x8;
typedef __attribute__((ext_vector_type(4))) float f32x4;

#define C2LE 2.8853900817779268f   // 2*log2(e)
#define LOG2E 1.4426950408889634f
#define AGENT __HIP_MEMORY_SCOPE_AGENT
#define RLX __ATOMIC_RELAXED

static __device__ __forceinline__ float blo(unsigned q) { return __uint_as_float(q << 16); }
static __device__ __forceinline__ float bhi(unsigned q) { return __uint_as_float(q & 0xFFFF0000u); }
static __device__ __forceinline__ float sigm(float x) {
  return __builtin_amdgcn_rcpf(1.0f + __builtin_amdgcn_exp2f(-x * LOG2E));
}
static __device__ __forceinline__ float tanhe(float x) {
  return fmaf(-2.0f, __builtin_amdgcn_rcpf(1.0f + __builtin_amdgcn_exp2f(x * C2LE)), 1.0f);
}
static __device__ __forceinline__ unsigned packhilo(float x) {
  __hip_bfloat16 h = __float2bfloat16(x);
  float r = x - __bfloat162float(h);
  __hip_bfloat16 l = __float2bfloat16(r);
  return (unsigned)__bfloat16_as_ushort(h) | ((unsigned)__bfloat16_as_ushort(l) << 16);
}
static __device__ __forceinline__ int swz(int e) { return e ^ ((e >> 4) & 7); }

// ---------------- pack kernels (validated layouts, unchanged) ----------------
__global__ void k_pack_whB(const float* __restrict__ wue, __hip_bfloat16* __restrict__ wp) {
  for (int idx = blockIdx.x * blockDim.x + threadIdx.x; idx < 262144;
       idx += gridDim.x * blockDim.x) {
    int j = idx & 7, l = (idx >> 3) & 63, kap = (idx >> 9) & 15, nb = (idx >> 13) & 3,
        sl = idx >> 15;
    int o = sl * 64 + nb * 16 + (l & 15);
    int dim = kap * 32 + (l >> 4) * 8 + j;
    wp[idx] = __float2bfloat16(wue[o * 1024 + dim]);
  }
}
__global__ void k_pack_w3B(const float* __restrict__ wih, const float* __restrict__ whh,
                           __hip_bfloat16* __restrict__ wp) {
  for (int idx = blockIdx.x * blockDim.x + threadIdx.x; idx < 393216;
       idx += gridDim.x * blockDim.x) {
    int j = idx & 7, l = (idx >> 3) & 63;
    int ks = (idx >> 9) % 12, r = (idx >> 9) / 12;
    int nb = r & 7, sl = r >> 3;
    int n = nb * 16 + (l & 15);
    int g = (n >> 5) * 256 + sl * 32 + (n & 31);
    int k = ks * 32 + (l >> 4) * 8 + j;
    float v = (k < 128) ? wih[g * 128 + k] : whh[g * 256 + (k - 128)];
    wp[idx] = __float2bfloat16(v);
  }
}
__global__ void k_bsum(const float* __restrict__ bih, const float* __restrict__ bhh,
                       float* __restrict__ bs) {
  int idx = blockIdx.x * blockDim.x + threadIdx.x;
  if (idx < 1024) bs[idx] = bih[idx] + bhh[idx];
}
__global__ void k_wxt(const float* __restrict__ wue, float* __restrict__ wxt) {
  for (int idx = blockIdx.x * blockDim.x + threadIdx.x; idx < 512 * 512;
       idx += gridDim.x * blockDim.x) {
    int o = idx & 511, s = idx >> 9;
    wxt[idx] = wue[o * 1024 + 512 + s];
  }
}

// proj_x: px2[b][d][s] = bf16( exp2(C2LE * proj_x[b,d,s]) )   [Epx]
__global__ __launch_bounds__(512) void k_projx(const float* __restrict__ x,
                                               const float* __restrict__ wxt,
                                               __hip_bfloat16* __restrict__ px2) {
  __shared__ alignas(16) float xsT[32][512];
  const int b = blockIdx.x;
  const int tid = threadIdx.x;
  for (int dt = 0; dt < 4; ++dt) {
    __syncthreads();
    const float4* xr = (const float4*)(x + ((size_t)b << 16) + (size_t)tid * 128 + dt * 32);
#pragma unroll
    for (int q = 0; q < 8; ++q) {
      float4 vx = xr[q];
      xsT[q * 4 + 0][tid] = vx.x;
      xsT[q * 4 + 1][tid] = vx.y;
      xsT[q * 4 + 2][tid] = vx.z;
      xsT[q * 4 + 3][tid] = vx.w;
    }
    __syncthreads();
    const int o = tid;
    float acc[32];
#pragma unroll
    for (int dd = 0; dd < 32; ++dd) acc[dd] = 0.f;
    for (int s4 = 0; s4 < 128; ++s4) {
      float w0 = wxt[(s4 * 4 + 0) * 512 + o];
      float w1 = wxt[(s4 * 4 + 1) * 512 + o];
      float w2 = wxt[(s4 * 4 + 2) * 512 + o];
      float w3 = wxt[(s4 * 4 + 3) * 512 + o];
#pragma unroll
      for (int dd = 0; dd < 32; ++dd) {
        float4 xv = *(const float4*)&xsT[dd][s4 * 4];
        acc[dd] = fmaf(w0, xv.x, fmaf(w1, xv.y, fmaf(w2, xv.z, fmaf(w3, xv.w, acc[dd]))));
      }
    }
    for (int dd = 0; dd < 32; ++dd) {
      px2[((size_t)b * 128 + dt * 32 + dd) * 512 + o] =
          __float2bfloat16(__builtin_amdgcn_exp2f(acc[dd] * C2LE));
    }
  }
}

// ---------------- main persistent kernel: 32 groups x 8 blocks (R12/R14 structure) ----
__global__ __launch_bounds__(1024) void k_main(
    const __hip_bfloat16* __restrict__ px2, const __hip_bfloat16* __restrict__ whB,
    const __hip_bfloat16* __restrict__ w3B, const float* __restrict__ bsum,
    const float* __restrict__ x, const float* __restrict__ ve,
    unsigned* __restrict__ hG, float* __restrict__ Eg, unsigned* __restrict__ ctrs,
    float* __restrict__ out) {
  __shared__ alignas(16) __hip_bfloat16 w3_l[49152];  // 96 KB W3 B-frags
  __shared__ alignas(16) uint4 hAhi[1024];            // 16 KB hi-frags (swizzled)
  __shared__ alignas(16) uint4 hAlo[1024];            // 16 KB lo-frags
  __shared__ alignas(16) uint4 uAhi[256];             // 4 KB
  __shared__ alignas(16) uint4 uAlo[256];             // 4 KB
  __shared__ float PHp[4][8][64];                     // 8 KB
  __shared__ float PH[512];                           // 2 KB   ePH = exp2(C2LE*ph)
  __shared__ float gp[2][128][9];                     // 9 KB (padded stride)
  __shared__ float c_l[32][9];                        // 1.1 KB (padded)
  __shared__ float v_l[64];
  __shared__ float bs_l[128];
  __shared__ float vss_sh;

  const int grp = blockIdx.x & 31;  // 8 member blocks share blockIdx%32 -> same XCD
  const int sl = blockIdx.x >> 5;   // slice 0..7
  const int tid = threadIdx.x;
  const int lane = tid & 63;
  const int w = tid >> 6;
  const int b2 = tid >> 7;  // phase2 mapping
  const int d2 = tid & 127;
  const int bG2 = grp * 8 + b2;

  // ---- prologue
  {
    const uint4* src = (const uint4*)(w3B + (size_t)sl * 49152);
    uint4* dst = (uint4*)w3_l;
    for (int i = tid; i < 6144; i += 1024) dst[i] = src[i];
  }
  bf16x8 whr[4];
  {
    const bf16x8* src =
        (const bf16x8*)whB + ((size_t)(sl * 4 + (w & 3)) * 16 + (w >> 2) * 4) * 64 + lane;
#pragma unroll
    for (int i = 0; i < 4; ++i) whr[i] = src[i * 64];
  }
  uint4 pxr[8];  // bf16 Epx pairs for our (b2,d2), 64 s
  {
    const uint4* p4 = (const uint4*)(px2 + ((size_t)bG2 * 128 + d2) * 512 + sl * 64);
#pragma unroll
    for (int i = 0; i < 8; ++i) pxr[i] = p4[i];
  }
  if (tid < 64) v_l[tid] = ve[sl * 64 + tid];
  if (tid < 128) bs_l[tid] = bsum[(tid >> 5) * 256 + sl * 32 + (tid & 31)];
  if (tid < 256) c_l[tid >> 3][tid & 7] = 0.f;
  {
    uint4 z = {0, 0, 0, 0};
    hAhi[tid] = z;
    hAlo[tid] = z;
    if (tid < 256) {
      uAhi[tid] = z;
      uAlo[tid] = z;
    }
  }
  if (tid == 0) {
    float s = 0.f;
    for (int i = 0; i < 64; ++i) s += ve[sl * 64 + i];
    vss_sh = s;
  }
  __syncthreads();
  const float vss = vss_sh;
  unsigned* ctrA = ctrs + grp * 64;
  unsigned* ctrB = ctrA + 32;
  // softmax-thread x data (tid<512): b = tid>>6, dims (2k, 2k+1), k = tid&63
  float2 xv2;
  if (tid < 512)
    xv2 = *(const float2*)&x[((size_t)(grp * 8 + (tid >> 6)) * 512) * 128 + 2 * (tid & 63)];

  for (int t = 0; t < 512; ++t) {
    const int par = t & 1;

    // ---- stage h/c hi/lo frag-words straight into LDS (loop top = pure stage traffic)
    {
      const unsigned long long* hp =
          (const unsigned long long*)(hG + (size_t)(par * 32 + grp) * 4096);
      int E = tid >> 1, which = tid & 1;
      const unsigned long long* src = hp + which * 1024 + E * 2;
      unsigned long long a0 = __hip_atomic_load(src, RLX, AGENT);
      unsigned long long a1 = __hip_atomic_load(src + 1, RLX, AGENT);
      int ep = swz(((E >> 3) << 4) + (E & 7));
      uint4 q;
      q.x = (unsigned)a0;
      q.y = (unsigned)(a0 >> 32);
      q.z = (unsigned)a1;
      q.w = (unsigned)(a1 >> 32);
      if (which) hAlo[ep] = q;
      else hAhi[ep] = q;
    }
    __syncthreads();

    // ---- Phase 1: PH[8b, 64o] = hs x Wh (16 waves = 4nb x 4kq; hi+lo passes)
    {
      const int kq = w >> 2, nb = w & 3;
      f32x4 acc = {0.f, 0.f, 0.f, 0.f};
#pragma unroll
      for (int i = 0; i < 4; ++i) {
        int ep = swz((kq * 4 + i) * 64 + lane);
        bf16x8 ahi = *(const bf16x8*)&hAhi[ep];
        bf16x8 alo = *(const bf16x8*)&hAlo[ep];
        acc = __builtin_amdgcn_mfma_f32_16x16x32_bf16(ahi, whr[i], acc, 0, 0, 0);
        acc = __builtin_amdgcn_mfma_f32_16x16x32_bf16(alo, whr[i], acc, 0, 0, 0);
      }
      if (lane < 32) {
        int r16 = lane >> 4, c16 = lane & 15;
#pragma unroll
        for (int rr = 0; rr < 4; ++rr) PHp[kq][r16 * 4 + rr][nb * 16 + c16] = acc[rr];
      }
    }
    __syncthreads();
    if (tid < 512) {
      float s = (PHp[0][tid >> 6][tid & 63] + PHp[1][tid >> 6][tid & 63] +
                 PHp[2][tid >> 6][tid & 63] + PHp[3][tid >> 6][tid & 63]);
      PH[tid] = __builtin_amdgcn_exp2f(s * C2LE);  // ePH
    }
    __syncthreads();

    // ---- Phase 2: E partial over our 64 s for (b2,d2): r = 1/(1 + Epx*ePH)
    {
      float R = 0.f;
      const float* PHb = &PH[b2 * 64];
#pragma unroll 2
      for (int s8 = 0; s8 < 8; ++s8) {
        uint4 q = pxr[s8];
        float4 pa = *(const float4*)&PHb[s8 * 8];
        float4 pb = *(const float4*)&PHb[s8 * 8 + 4];
        float4 va = *(const float4*)&v_l[s8 * 8];
        float4 vb = *(const float4*)&v_l[s8 * 8 + 4];
        R = fmaf(va.x, __builtin_amdgcn_rcpf(fmaf(blo(q.x), pa.x, 1.0f)), R);
        R = fmaf(va.y, __builtin_amdgcn_rcpf(fmaf(bhi(q.x), pa.y, 1.0f)), R);
        R = fmaf(va.z, __builtin_amdgcn_rcpf(fmaf(blo(q.y), pa.z, 1.0f)), R);
        R = fmaf(va.w, __builtin_amdgcn_rcpf(fmaf(bhi(q.y), pa.w, 1.0f)), R);
        R = fmaf(vb.x, __builtin_amdgcn_rcpf(fmaf(blo(q.z), pb.x, 1.0f)), R);
        R = fmaf(vb.y, __builtin_amdgcn_rcpf(fmaf(bhi(q.z), pb.y, 1.0f)), R);
        R = fmaf(vb.z, __builtin_amdgcn_rcpf(fmaf(blo(q.w), pb.z, 1.0f)), R);
        R = fmaf(vb.w, __builtin_amdgcn_rcpf(fmaf(bhi(q.w), pb.w, 1.0f)), R);
      }
      __hip_atomic_fetch_add(Eg + (size_t)(par * 32 + grp) * 1024 + b2 * 128 + d2,
                             fmaf(-2.f, R, vss), RLX, AGENT);
    }

    // ---- Phase 3h part 1 (3 of 4 ksteps) hides the E-atomicAdd flight
    const int nb3 = w & 7, kh3 = w >> 3;
    f32x4 acc3 = {0.f, 0.f, 0.f, 0.f};
#pragma unroll
    for (int i = 0; i < 3; ++i) {
      int ks = 4 + kh3 * 4 + i;  // h ksteps 4..11 -> hA labels 0..511
      int ep = swz((ks - 4) * 64 + lane);
      bf16x8 ahi = *(const bf16x8*)&hAhi[ep];
      bf16x8 alo = *(const bf16x8*)&hAlo[ep];
      bf16x8 bf = ((const bf16x8*)w3_l)[((size_t)nb3 * 12 + ks) * 64 + lane];
      acc3 = __builtin_amdgcn_mfma_f32_16x16x32_bf16(ahi, bf, acc3, 0, 0, 0);
      acc3 = __builtin_amdgcn_mfma_f32_16x16x32_bf16(alo, bf, acc3, 0, 0, 0);
    }
    // ---- barrier A (arrive; fill poll window with next-par E-zero stores; poll)
    __syncthreads();  // drains E-adds
    if (tid == 0) __hip_atomic_fetch_add(ctrA, 1u, RLX, AGENT);
    if (tid < 128)
      __hip_atomic_store(Eg + (size_t)((1 - par) * 32 + grp) * 1024 + sl * 128 + tid, 0.f, RLX,
                         AGENT);
    if (tid == 0) {
      while (__hip_atomic_load(ctrA, RLX, AGENT) < 8u * (t + 1)) __builtin_amdgcn_s_sleep(1);
    }
    __syncthreads();

    // ---- issue E read early (MALL RT), cover it with P3h part 2 (last kstep)
    float2 Ev;
    if (tid < 512)
      Ev = *(const float2*)&((
          const float*)Eg)[(size_t)(par * 32 + grp) * 1024 + (tid >> 6) * 128 + 2 * (tid & 63)];
    {
      int ks = 4 + kh3 * 4 + 3;
      int ep = swz((ks - 4) * 64 + lane);
      bf16x8 ahi = *(const bf16x8*)&hAhi[ep];
      bf16x8 alo = *(const bf16x8*)&hAlo[ep];
      bf16x8 bf = ((const bf16x8*)w3_l)[((size_t)nb3 * 12 + ks) * 64 + lane];
      acc3 = __builtin_amdgcn_mfma_f32_16x16x32_bf16(ahi, bf, acc3, 0, 0, 0);
      acc3 = __builtin_amdgcn_mfma_f32_16x16x32_bf16(alo, bf, acc3, 0, 0, 0);
    }

    // ---- softmax (512 threads; one wave per batch; d-pairs)
    if (tid < 512) {
      const int bs = tid >> 6, k = tid & 63;
      float e0 = __builtin_amdgcn_exp2f(Ev.x * LOG2E);
      float e1 = __builtin_amdgcn_exp2f(Ev.y * LOG2E);
      float z = e0 + e1;
#pragma unroll
      for (int m = 1; m < 64; m <<= 1) z += __shfl_xor(z, m);
      float zinv = __builtin_amdgcn_rcpf(z);
      float u0 = xv2.x * e0 * zinv, u1 = xv2.y * e1 * zinv;
      unsigned pk0 = packhilo(u0), pk1 = packhilo(u1);
      unsigned whi = __builtin_amdgcn_perm(pk1, pk0, 0x05040100u);
      unsigned wlo = __builtin_amdgcn_perm(pk1, pk0, 0x07060302u);
      int d0 = 2 * k;
      int ep = swz((d0 >> 5) * 64 + ((d0 >> 3) & 3) * 16 + bs);
      int j2 = (d0 >> 1) & 3;
      ((unsigned*)&uAhi[ep])[j2] = whi;
      ((unsigned*)&uAlo[ep])[j2] = wlo;
    }
    __syncthreads();

    // ---- Phase 3u: u-part of gates (ks 0..3)
#pragma unroll
    for (int i = 0; i < 2; ++i) {
      int ks = kh3 * 2 + i;
      int ep = swz(ks * 64 + lane);
      bf16x8 ahi = *(const bf16x8*)&uAhi[ep];
      bf16x8 alo = *(const bf16x8*)&uAlo[ep];
      bf16x8 bf = ((const bf16x8*)w3_l)[((size_t)nb3 * 12 + ks) * 64 + lane];
      acc3 = __builtin_amdgcn_mfma_f32_16x16x32_bf16(ahi, bf, acc3, 0, 0, 0);
      acc3 = __builtin_amdgcn_mfma_f32_16x16x32_bf16(alo, bf, acc3, 0, 0, 0);
    }
    if (lane < 32) {
      int r16 = lane >> 4, c16 = lane & 15;
#pragma unroll
      for (int rr = 0; rr < 4; ++rr) gp[kh3][nb3 * 16 + c16][r16 * 4 + rr] = acc3[rr];
    }
    __syncthreads();

    // ---- Phase 4: LSTM pointwise (coalesced mapping: bb=tid>>5, jj=tid&31)
    float h_new;
    int bb = tid >> 5, jj = tid & 31;
    if (tid < 256) {
      float gi = gp[0][jj][bb] + gp[1][jj][bb] + bs_l[jj];
      float gf = gp[0][32 + jj][bb] + gp[1][32 + jj][bb] + bs_l[32 + jj];
      float gg = gp[0][64 + jj][bb] + gp[1][64 + jj][bb] + bs_l[64 + jj];
      float go = gp[0][96 + jj][bb] + gp[1][96 + jj][bb] + bs_l[96 + jj];
      float i_ = sigm(gi), f_ = sigm(gf), g_ = tanhe(gg), o_ = sigm(go);
      float c_new = fmaf(f_, c_l[jj][bb], i_ * g_);
      h_new = o_ * tanhe(c_new);
      c_l[jj][bb] = c_new;
      // publish pre-split hi/lo words (pairs jj, jj^1 via shfl)
      unsigned pkh = packhilo(h_new), pkc = packhilo(c_new);
      unsigned prh = __shfl_xor(pkh, 1), prc = __shfl_xor(pkc, 1);
      int dd = sl * 32 + jj;
      int E = ((dd >> 5) * 4 + ((dd >> 3) & 3)) * 8 + bb;
      int j2 = (dd & 7) >> 1;
      unsigned* hw = hG + (size_t)((1 - par) * 32 + grp) * 4096;
      if ((jj & 1) == 0) {  // hi words: low16 = mine, high16 = partner
        __hip_atomic_store(hw + E * 4 + j2, __builtin_amdgcn_perm(prh, pkh, 0x05040100u), RLX,
                           AGENT);
        __hip_atomic_store(hw + (E + 256) * 4 + j2, __builtin_amdgcn_perm(prc, pkc, 0x05040100u),
                           RLX, AGENT);
      } else {  // lo words: low16 = partner's lo, high16 = mine's lo
        __hip_atomic_store(hw + 2048 + E * 4 + j2, __builtin_amdgcn_perm(pkh, prh, 0x07060302u),
                           RLX, AGENT);
        __hip_atomic_store(hw + 2048 + (E + 256) * 4 + j2,
                           __builtin_amdgcn_perm(pkc, prc, 0x07060302u), RLX, AGENT);
      }
    }
    // ---- barrier B; fill poll window with coalesced out-store + next-x prefetch
    __syncthreads();
    if (tid == 0) __hip_atomic_fetch_add(ctrB, 1u, RLX, AGENT);
    if (tid < 256)
      __builtin_nontemporal_store(h_new,
                                  out + ((size_t)t * 256 + grp * 8 + bb) * 256 + sl * 32 + jj);
    float2 xv2n;
    if (tid < 512) {
      int tn = (t < 511) ? t + 1 : 511;
      xv2n = *(const float2*)&x[((size_t)(grp * 8 + (tid >> 6)) * 512 + tn) * 128 + 2 * (tid & 63)];
    }
    if (tid == 0) {
      while (__hip_atomic_load(ctrB, RLX, AGENT) < 8u * (t + 1)) __builtin_amdgcn_s_sleep(1);
    }
    __syncthreads();
    xv2 = xv2n;
  }
}

// ---------------- host ----------------
extern "C" void kernel_launch(void* const* d_in, const int* in_sizes, int n_in,
                              void* d_out, int out_size, void* d_ws, size_t ws_size,
                              hipStream_t stream) {
  const float* x = (const float*)d_in[0];
  const float* wue = (const float*)d_in[1];
  const float* ve = (const float*)d_in[2];
  const float* wih = (const float*)d_in[3];
  const float* whh = (const float*)d_in[4];
  const float* bih = (const float*)d_in[5];
  const float* bhh = (const float*)d_in[6];
  float* out = (float*)d_out;

  char* ws = (char*)d_ws;
  __hip_bfloat16* px2 = (__hip_bfloat16*)(ws);             // 33,554,432 B
  __hip_bfloat16* whB = (__hip_bfloat16*)(ws + 33554432);  //    524,288 B
  __hip_bfloat16* w3B = (__hip_bfloat16*)(ws + 34078720);  //    786,432 B
  float* bsum = (float*)(ws + 34865152);                   //      4,096 B
  float* Eg = (float*)(ws + 34869248);                     //    262,144 B
  unsigned* ctrs = (unsigned*)(ws + 35131392);             //      8,192 B
  unsigned* hG = (unsigned*)(ws + 35139584);               //  1,048,576 B
  float* wxt = (float*)(ws + 36188160);                    //  1,048,576 B
  // total: 37,236,736 B

  k_pack_whB<<<1024, 256, 0, stream>>>(wue, whB);
  k_pack_w3B<<<1024, 256, 0, stream>>>(wih, whh, w3B);
  k_bsum<<<4, 256, 0, stream>>>(bih, bhh, bsum);
  k_wxt<<<256, 256, 0, stream>>>(wue, wxt);
  k_projx<<<256, 512, 0, stream>>>(x, wxt, px2);
  hipMemsetAsync(hG, 0, 1048576, stream);
  hipMemsetAsync(Eg, 0, 262144, stream);
  hipMemsetAsync(ctrs, 0, 8192, stream);
  k_main<<<256, 1024, 0, stream>>>(px2, whB, w3B, bsum, x, ve, hG, Eg, ctrs, out);
}